// Round 5
// baseline (127.621 us; speedup 1.0000x reference)
//
#include <hip/hip_runtime.h>

#define DD 256
#define BB 8
#define SS 1024
#define XSTRIDE 264   // f16 elems per LDS row (528 B, 16B-aligned)
#define RSTRIDE 132   // f32 elems per residual LDS row (col-half, 528 B)

// ws layout (bytes): L1 tabs 262144 | L2 tabs 262144 | y1 f32 8388608
#define LAYER_BYTES 262144
#define PTAB_OFF    131072
#define Y1_OFF      (2 * LAYER_BYTES)
#define Y1_BYTES    (BB * SS * DD * 4)
#define WS_NEEDED   (Y1_OFF + Y1_BYTES)

typedef _Float16 half8  __attribute__((ext_vector_type(8)));
typedef _Float16 half2t __attribute__((ext_vector_type(2)));
typedef __fp16   fp16x2 __attribute__((ext_vector_type(2)));
typedef __attribute__((ext_vector_type(4))) float float4v;

union h8u { half8 h; half2t h2[4]; };

__device__ __forceinline__ half2t pkrtz(float a, float b) {
    union { fp16x2 f; half2t h; } cv;
    cv.f = __builtin_amdgcn_cvt_pkrtz(a, b);
    return cv.h;
}

__device__ __forceinline__ float cosrev(float x) {   // cos(2*pi*x)
    return __builtin_amdgcn_cosf(__builtin_amdgcn_fractf(x));
}

// Fragment-ordered f16 tables: for gi = (kt*16 + wt)*64 + lane,
// lane = quad*16 + l15, n = 16*wt+l15, j0 = kt*32+quad*8:
//   Mtab[gi] = M[n][j0..j0+7], Ptab[gi] = P[n][j0..j0+7]
__global__ void build_tabs(const float* __restrict__ M1, const float* __restrict__ P1,
                           const float* __restrict__ M2, const float* __restrict__ P2,
                           char* __restrict__ ws)
{
    int gid   = blockIdx.x * 256 + threadIdx.x;   // 0..16383
    int layer = gid >> 13;
    int gi    = gid & 8191;
    int idx   = gi >> 6;                           // kt*16 + wt
    int lane  = gi & 63;
    int wt    = idx & 15;
    int l15   = lane & 15, quad = lane >> 4;
    int kt    = idx >> 4;
    int n     = 16 * wt + l15;
    int j0    = kt * 32 + quad * 8;

    const float* Msrc = layer ? M2 : M1;
    const float* Psrc = layer ? P2 : P1;

    h8u mh, ph;
    #pragma unroll
    for (int e = 0; e < 4; ++e) {
        float ma = Msrc[(size_t)n * DD + j0 + 2 * e];
        float mb = Msrc[(size_t)n * DD + j0 + 2 * e + 1];
        float pa = Psrc[(size_t)n * DD + j0 + 2 * e];
        float pb = Psrc[(size_t)n * DD + j0 + 2 * e + 1];
        mh.h2[e] = pkrtz(ma, mb);
        ph.h2[e] = pkrtz(pa, pb);
    }
    char* base = ws + (size_t)layer * LAYER_BYTES;
    ((half8*)base)[gi]              = mh.h;
    ((half8*)(base + PTAB_OFF))[gi] = ph.h;
}

// One layer, col-split. Grid 1024 = (s-pair sp) x (col-half ch); block 512 thr (8 waves).
// 4 blocks/CU = 32 waves/CU (max occupancy; round-4 measured duty 52% at 16 waves/CU,
// round-2 measured 65% at 32 -- occupancy is the lever, this split is work-conserving:
// each cos/rcp is computed exactly once chip-wide; phase A+LN duplicated x2 (cheap).
// Phase A: wave w computes n-tiles 2w,2w+1 -> full 256-col xt (needed for LN + K=256).
// Phase B: wave w computes only n-tile ch*8+w (its col-half). dst = y1 or out (f32).
__global__ __launch_bounds__(512, 8)
void split_layer(const float* __restrict__ src,     // [B,S,D] f32 layer input
                 const char*  __restrict__ lbase,   // this layer's Mtab|Ptab
                 const float* __restrict__ g,
                 const float* __restrict__ be,
                 float* __restrict__ dst)            // [B,S,D] f32 layer output
{
    __shared__ __align__(16) _Float16 xsb[16][XSTRIDE];  // staged input, f16, A-layout
    __shared__ __align__(16) _Float16 xtb[16][XSTRIDE];  // LN'd xt, f16 (full width)
    __shared__ __align__(16) float2 stats[16][8];        // [row][wave] (sum, sumsq)
    __shared__ __align__(16) float res_lds[16][RSTRIDE]; // f32 residual, own col-half

    const half8* Mtab = (const half8*)lbase;
    const half8* Ptab = (const half8*)(lbase + PTAB_OFF);

    const int tid  = threadIdx.x;
    const int w    = tid >> 6;
    const int lane = tid & 63;
    const int l15  = lane & 15;
    const int quad = lane >> 4;
    const int sp   = blockIdx.x >> 1;
    const int ch   = blockIdx.x & 1;      // col half: cols ch*128 .. ch*128+127
    const int s0   = sp * 2;
    const float k0 = (float)s0;

    // ---- stage rows r = sl*8+b: full width to xsb (f16), own half to res_lds (f32)
    {
        const float4* src4 = (const float4*)src;
        #pragma unroll
        for (int u = 0; u < 2; ++u) {
            int v  = tid + 512 * u;          // float4 index 0..1023
            int sl = v >> 9;
            int rm = v & 511;
            int b  = rm >> 6, j4 = rm & 63;
            float4 x = src4[((size_t)b * SS + s0 + sl) * 64 + j4];
            int r = sl * 8 + b;
            half2t* d2 = (half2t*)&xsb[r][4 * j4];
            d2[0] = pkrtz(x.x, x.y);
            d2[1] = pkrtz(x.z, x.w);
            if ((j4 >> 5) == ch)
                *(float4*)&res_lds[r][4 * (j4 & 31)] = x;
        }
    }
    __syncthreads();

    // ======== phase A: xt = x @ M^T (full width), distance-1 pipelined
    float4v acc1[2];
    acc1[0] = (float4v){0.f, 0.f, 0.f, 0.f};
    acc1[1] = (float4v){0.f, 0.f, 0.f, 0.f};

    half8 aN  = *(const half8*)&xsb[l15][quad * 8];
    half8 b0N = Mtab[(2 * w) * 64 + lane];
    half8 b1N = Mtab[(2 * w + 1) * 64 + lane];
    #pragma unroll 1
    for (int kt = 0; kt < 8; ++kt) {
        half8 aC = aN, b0C = b0N, b1C = b1N;
        if (kt < 7) {
            aN  = *(const half8*)&xsb[l15][(kt + 1) * 32 + quad * 8];
            b0N = Mtab[((kt + 1) * 16 + 2 * w) * 64 + lane];
            b1N = Mtab[((kt + 1) * 16 + 2 * w + 1) * 64 + lane];
        }
        acc1[0] = __builtin_amdgcn_mfma_f32_16x16x32_f16(aC, b0C, acc1[0], 0, 0, 0);
        acc1[1] = __builtin_amdgcn_mfma_f32_16x16x32_f16(aC, b1C, acc1[1], 0, 0, 0);
    }

    // issue phase-B's first Ptab load now: LN below covers its latency
    half8 pN = Ptab[(ch * 8 + w) * 64 + lane];

    // ======== LayerNorm in C-register layout (row m = quad*4+reg)
    #pragma unroll
    for (int reg = 0; reg < 4; ++reg) {
        float v0 = acc1[0][reg], v1 = acc1[1][reg];
        float sm = v0 + v1;
        float sq = fmaf(v0, v0, v1 * v1);
        #pragma unroll
        for (int off = 1; off < 16; off <<= 1) {
            sm += __shfl_xor(sm, off, 64);
            sq += __shfl_xor(sq, off, 64);
        }
        if (l15 == 0) stats[quad * 4 + reg][w] = make_float2(sm, sq);
    }
    __syncthreads();
    {
        int c0i = 16 * (2 * w) + l15, c1i = 16 * (2 * w + 1) + l15;
        float gv0 = g[c0i], bv0 = be[c0i];
        float gv1 = g[c1i], bv1 = be[c1i];
        #pragma unroll
        for (int reg = 0; reg < 4; ++reg) {
            int m = quad * 4 + reg;
            const float4* s4 = (const float4*)&stats[m][0];
            float4 q0 = s4[0], q1 = s4[1], q2 = s4[2], q3 = s4[3];
            float sm = (q0.x + q0.z) + (q1.x + q1.z) + (q2.x + q2.z) + (q3.x + q3.z);
            float sq = (q0.y + q0.w) + (q1.y + q1.w) + (q2.y + q2.w) + (q3.y + q3.w);
            float mm = sm * (1.f / DD);
            float rs = rsqrtf(sq * (1.f / DD) - mm * mm + 1e-5f);
            xtb[m][c0i] = (_Float16)fmaf((acc1[0][reg] - mm) * rs, gv0, bv0);
            xtb[m][c1i] = (_Float16)fmaf((acc1[1][reg] - mm) * rs, gv1, bv1);
        }
    }
    __syncthreads();   // xtb ready

    // ======== phase B: own n-tile only; W = P * cos, 1/p via v_rcp (k0,k0+1 share it)
    float4v accS[2];   // [s-half]
    accS[0] = (float4v){0.f, 0.f, 0.f, 0.f};
    accS[1] = (float4v){0.f, 0.f, 0.f, 0.f};

    const int nB = 16 * (ch * 8 + w) + l15;           // phase-B row of W
    float fb = (float)(nB * DD + quad * 8 + 2);       // exact int in f32 (< 2^17)
    half8 aBN = *(const half8*)&xtb[l15][quad * 8];

    #pragma unroll 1
    for (int kt = 0; kt < 8; ++kt) {
        half8 aC = aBN;
        h8u pC; pC.h = pN;
        if (kt < 7) {
            aBN = *(const half8*)&xtb[l15][(kt + 1) * 32 + quad * 8];
            pN  = Ptab[((kt + 1) * 16 + ch * 8 + w) * 64 + lane];
        }
        h8u bA, bB;
        #pragma unroll
        for (int e = 0; e < 4; ++e) {
            float ia = __builtin_amdgcn_rcpf(fb + (float)(2 * e));
            float ib = __builtin_amdgcn_rcpf(fb + (float)(2 * e + 1));
            float a0 = k0 * ia, b0f = k0 * ib;
            float a1 = a0 + ia, b1f = b0f + ib;        // (k0+1)/p
            half2t c0 = pkrtz(cosrev(a0), cosrev(b0f));
            half2t c1 = pkrtz(cosrev(a1), cosrev(b1f));
            bA.h2[e] = pC.h2[e] * c0;                  // v_pk_mul_f16
            bB.h2[e] = pC.h2[e] * c1;
        }
        accS[0] = __builtin_amdgcn_mfma_f32_16x16x32_f16(aC, bA.h, accS[0], 0, 0, 0);
        accS[1] = __builtin_amdgcn_mfma_f32_16x16x32_f16(aC, bB.h, accS[1], 0, 0, 0);
        fb += 32.0f;
    }

    // ======== epilogue: rows 0-7 (quads 0-1) = s0, rows 8-15 (quads 2-3) = s1
    {
        int col = nB;                  // global col; local col = 16*w + l15
        int cl  = 16 * w + l15;
        float4v av = (quad < 2) ? accS[0] : accS[1];
        int sl = quad >> 1;
        #pragma unroll
        for (int reg = 0; reg < 4; ++reg) {
            int m = quad * 4 + reg;
            int b = m & 7;
            dst[((size_t)b * SS + s0 + sl) * DD + col] = av[reg] + res_lds[m][cl];
        }
    }
}

// ---- fallback (no workspace): round-4 fused kernel, direct M/P loads ----
__global__ __launch_bounds__(512, 4)
void fused_fallback(const float* __restrict__ seq,
                    const float* __restrict__ M1, const float* __restrict__ P1,
                    const float* __restrict__ g1, const float* __restrict__ be1,
                    const float* __restrict__ M2, const float* __restrict__ P2,
                    const float* __restrict__ g2, const float* __restrict__ be2,
                    float* __restrict__ out)
{
    __shared__ __align__(16) _Float16 xsb[16][XSTRIDE];
    __shared__ __align__(16) _Float16 xtb[16][XSTRIDE];
    __shared__ __align__(16) float2 stats[16][8];
    __shared__ __align__(16) float res_lds[16][2 * RSTRIDE];

    const int tid  = threadIdx.x;
    const int w    = tid >> 6;
    const int lane = tid & 63;
    const int l15  = lane & 15;
    const int quad = lane >> 4;
    const int s0   = blockIdx.x * 2;
    const float k0 = (float)s0;

    {
        const float4* seq4 = (const float4*)seq;
        #pragma unroll
        for (int u = 0; u < 2; ++u) {
            int v  = tid + 512 * u;
            int sl = v >> 9;
            int rm = v & 511;
            int b  = rm >> 6, j4 = rm & 63;
            float4 x = seq4[((size_t)b * SS + s0 + sl) * 64 + j4];
            int r = sl * 8 + b;
            half2t* d2 = (half2t*)&xsb[r][4 * j4];
            d2[0] = pkrtz(x.x, x.y);
            d2[1] = pkrtz(x.z, x.w);
            *(float4*)&res_lds[r][4 * j4] = x;
        }
    }
    __syncthreads();

    #pragma unroll 1
    for (int layer = 0; layer < 2; ++layer) {
        const float* M  = layer ? M2  : M1;
        const float* P  = layer ? P2  : P1;
        const float* g  = layer ? g2  : g1;
        const float* be = layer ? be2 : be1;

        float4v acc1[2];
        acc1[0] = (float4v){0.f, 0.f, 0.f, 0.f};
        acc1[1] = (float4v){0.f, 0.f, 0.f, 0.f};

        #pragma unroll 1
        for (int kt = 0; kt < 8; ++kt) {
            half8 a = *(const half8*)&xsb[l15][kt * 32 + quad * 8];
            #pragma unroll
            for (int t = 0; t < 2; ++t) {
                int n = 16 * (2 * w + t) + l15;
                const float4* Mr = (const float4*)M + ((size_t)n * 64 + kt * 8 + quad * 2);
                float4 m0 = Mr[0], m1 = Mr[1];
                h8u bb2;
                bb2.h2[0] = pkrtz(m0.x, m0.y);
                bb2.h2[1] = pkrtz(m0.z, m0.w);
                bb2.h2[2] = pkrtz(m1.x, m1.y);
                bb2.h2[3] = pkrtz(m1.z, m1.w);
                acc1[t] = __builtin_amdgcn_mfma_f32_16x16x32_f16(a, bb2.h, acc1[t], 0, 0, 0);
            }
        }

        #pragma unroll
        for (int reg = 0; reg < 4; ++reg) {
            float v0 = acc1[0][reg], v1 = acc1[1][reg];
            float sm = v0 + v1;
            float sq = fmaf(v0, v0, v1 * v1);
            #pragma unroll
            for (int off = 1; off < 16; off <<= 1) {
                sm += __shfl_xor(sm, off, 64);
                sq += __shfl_xor(sq, off, 64);
            }
            if (l15 == 0) stats[quad * 4 + reg][w] = make_float2(sm, sq);
        }
        __syncthreads();
        {
            int c0i = 16 * (2 * w) + l15, c1i = 16 * (2 * w + 1) + l15;
            float gv0 = g[c0i], bv0 = be[c0i];
            float gv1 = g[c1i], bv1 = be[c1i];
            #pragma unroll
            for (int reg = 0; reg < 4; ++reg) {
                int m = quad * 4 + reg;
                const float4* s4 = (const float4*)&stats[m][0];
                float4 q0 = s4[0], q1 = s4[1], q2 = s4[2], q3 = s4[3];
                float sm = (q0.x + q0.z) + (q1.x + q1.z) + (q2.x + q2.z) + (q3.x + q3.z);
                float sq = (q0.y + q0.w) + (q1.y + q1.w) + (q2.y + q2.w) + (q3.y + q3.w);
                float mm = sm * (1.f / DD);
                float rs = rsqrtf(sq * (1.f / DD) - mm * mm + 1e-5f);
                xtb[m][c0i] = (_Float16)fmaf((acc1[0][reg] - mm) * rs, gv0, bv0);
                xtb[m][c1i] = (_Float16)fmaf((acc1[1][reg] - mm) * rs, gv1, bv1);
            }
        }
        __syncthreads();

        float4v accS[2][2];
        #pragma unroll
        for (int k = 0; k < 2; ++k)
            #pragma unroll
            for (int t = 0; t < 2; ++t) accS[k][t] = (float4v){0.f, 0.f, 0.f, 0.f};

        float fb0 = (float)((16 * (2 * w) + l15) * DD + quad * 8 + 2);
        float fb1 = fb0 + 16.0f * DD;

        #pragma unroll 1
        for (int kt = 0; kt < 8; ++kt) {
            half8 a = *(const half8*)&xtb[l15][kt * 32 + quad * 8];
            #pragma unroll
            for (int t = 0; t < 2; ++t) {
                int n = 16 * (2 * w + t) + l15;
                const float4* Pr = (const float4*)P + ((size_t)n * 64 + kt * 8 + quad * 2);
                float4 p0 = Pr[0], p1 = Pr[1];
                h8u pv;
                pv.h2[0] = pkrtz(p0.x, p0.y);
                pv.h2[1] = pkrtz(p0.z, p0.w);
                pv.h2[2] = pkrtz(p1.x, p1.y);
                pv.h2[3] = pkrtz(p1.z, p1.w);
                float fb = (t == 0) ? fb0 : fb1;
                h8u bA, bB;
                #pragma unroll
                for (int e = 0; e < 4; ++e) {
                    float ia = __builtin_amdgcn_rcpf(fb + (float)(2 * e));
                    float ib = __builtin_amdgcn_rcpf(fb + (float)(2 * e + 1));
                    float a0 = k0 * ia, b0f = k0 * ib;
                    float a1 = a0 + ia, b1f = b0f + ib;
                    half2t c0 = pkrtz(cosrev(a0), cosrev(b0f));
                    half2t c1 = pkrtz(cosrev(a1), cosrev(b1f));
                    bA.h2[e] = pv.h2[e] * c0;
                    bB.h2[e] = pv.h2[e] * c1;
                }
                accS[0][t] = __builtin_amdgcn_mfma_f32_16x16x32_f16(a, bA.h, accS[0][t], 0, 0, 0);
                accS[1][t] = __builtin_amdgcn_mfma_f32_16x16x32_f16(a, bB.h, accS[1][t], 0, 0, 0);
            }
            fb0 += 32.0f; fb1 += 32.0f;
        }

        #pragma unroll
        for (int t = 0; t < 2; ++t) {
            int col = 16 * (2 * w + t) + l15;
            float4v av = (quad < 2) ? accS[0][t] : accS[1][t];
            int sl = quad >> 1;
            #pragma unroll
            for (int reg = 0; reg < 4; ++reg) {
                int m = quad * 4 + reg;
                int b = m & 7;
                float val = av[reg] + res_lds[m][col];
                if (layer == 0) {
                    res_lds[m][col] = val;
                    xsb[m][col] = (_Float16)val;
                } else {
                    out[((size_t)b * SS + s0 + sl) * DD + col] = val;
                }
            }
        }
        if (layer == 0) __syncthreads();
    }
}

extern "C" void kernel_launch(void* const* d_in, const int* in_sizes, int n_in,
                              void* d_out, int out_size, void* d_ws, size_t ws_size,
                              hipStream_t stream)
{
    const float* seq = (const float*)d_in[0];
    const float* M1  = (const float*)d_in[1];
    const float* P1  = (const float*)d_in[2];
    const float* g1  = (const float*)d_in[3];
    const float* b1  = (const float*)d_in[4];
    const float* M2  = (const float*)d_in[5];
    const float* P2  = (const float*)d_in[6];
    const float* g2  = (const float*)d_in[7];
    const float* b2  = (const float*)d_in[8];
    float* out = (float*)d_out;

    if (ws_size >= WS_NEEDED) {
        char* ws = (char*)d_ws;
        float* y1 = (float*)(ws + Y1_OFF);
        build_tabs<<<64, 256, 0, stream>>>(M1, P1, M2, P2, ws);
        split_layer<<<SS, 512, 0, stream>>>(seq, ws, g1, b1, y1);
        split_layer<<<SS, 512, 0, stream>>>(y1, ws + LAYER_BYTES, g2, b2, out);
    } else {
        fused_fallback<<<SS / 2, 512, 0, stream>>>(
            seq, M1, P1, g1, b1, M2, P2, g2, b2, out);
    }
}

// Round 6
// 113.565 us; speedup vs baseline: 1.1238x; 1.1238x over previous
//
#include <hip/hip_runtime.h>

#define DD 256
#define BB 8
#define SS 1024
#define XSTRIDE 264   // f16 elems per LDS row (528 B, 16B-aligned)
#define RSTRIDE 260   // f32 elems per residual LDS row (1040 B, 16B-aligned)

// ws layout per layer (bytes): Mtab 131072 | Ptab 131072 (rcp on the fly)
#define LAYER_BYTES 262144
#define PTAB_OFF    131072
#define WS_NEEDED   (2 * LAYER_BYTES)

typedef _Float16 half8  __attribute__((ext_vector_type(8)));
typedef _Float16 half2t __attribute__((ext_vector_type(2)));
typedef __fp16   fp16x2 __attribute__((ext_vector_type(2)));
typedef __attribute__((ext_vector_type(4))) float float4v;

union h8u { half8 h; half2t h2[4]; };

__device__ __forceinline__ half2t pkrtz(float a, float b) {
    union { fp16x2 f; half2t h; } cv;
    cv.f = __builtin_amdgcn_cvt_pkrtz(a, b);
    return cv.h;
}

__device__ __forceinline__ float cosrev(float x) {   // cos(2*pi*x), any x (range-reduce)
    return __builtin_amdgcn_cosf(__builtin_amdgcn_fractf(x));
}

__device__ __forceinline__ float cosq(float x) {     // cos(2*pi*x), requires x in [0,1)
    return __builtin_amdgcn_cosf(x);
}

// Fragment-ordered f16 tables: for gi = (kt*16 + wt)*64 + lane,
// lane = quad*16 + l15, n = 16*wt+l15, j0 = kt*32+quad*8:
//   Mtab[gi] = M[n][j0..j0+7], Ptab[gi] = P[n][j0..j0+7]
__global__ void build_tabs(const float* __restrict__ M1, const float* __restrict__ P1,
                           const float* __restrict__ M2, const float* __restrict__ P2,
                           char* __restrict__ ws)
{
    int gid   = blockIdx.x * 256 + threadIdx.x;   // 0..16383
    int layer = gid >> 13;
    int gi    = gid & 8191;
    int idx   = gi >> 6;                           // kt*16 + wt
    int lane  = gi & 63;
    int wt    = idx & 15;
    int l15   = lane & 15, quad = lane >> 4;
    int kt    = idx >> 4;
    int n     = 16 * wt + l15;
    int j0    = kt * 32 + quad * 8;

    const float* Msrc = layer ? M2 : M1;
    const float* Psrc = layer ? P2 : P1;

    h8u mh, ph;
    #pragma unroll
    for (int e = 0; e < 4; ++e) {
        float ma = Msrc[(size_t)n * DD + j0 + 2 * e];
        float mb = Msrc[(size_t)n * DD + j0 + 2 * e + 1];
        float pa = Psrc[(size_t)n * DD + j0 + 2 * e];
        float pb = Psrc[(size_t)n * DD + j0 + 2 * e + 1];
        mh.h2[e] = pkrtz(ma, mb);
        ph.h2[e] = pkrtz(pa, pb);
    }
    char* base = ws + (size_t)layer * LAYER_BYTES;
    ((half8*)base)[gi]              = mh.h;
    ((half8*)(base + PTAB_OFF))[gi] = ph.h;
}

// Block = 512 threads (8 waves), s-pair (s0,s0+1) per block, grid 512 (work-optimal:
// each cos computed exactly once chip-wide; k0/k1 share one rcp; fused 2 layers keep
// phase A+LN un-duplicated -- round-5 showed any block-split duplicates >= 1.3x work
// for only ~1.25x duty). Busy-work attack: v_fract is skipped wherever the cos
// argument k/p is provably < 1: p = 256n + j + 2 >= 1026 > k for n >= 4, i.e. for
// every (w,t) except w==0,t==0 (wave-uniform branch). Bit-identical (fract(x)=x on [0,1)).
template<bool TABS>
__global__ __launch_bounds__(512, 4)
void fused_hierddpm(const float* __restrict__ seq,
                    const float* __restrict__ M1, const float* __restrict__ P1,
                    const float* __restrict__ g1, const float* __restrict__ be1,
                    const float* __restrict__ M2, const float* __restrict__ P2,
                    const float* __restrict__ g2, const float* __restrict__ be2,
                    const char* __restrict__ ws,
                    float* __restrict__ out)
{
    __shared__ __align__(16) _Float16 xsb[16][XSTRIDE];  // input / layer-out, f16, A-layout
    __shared__ __align__(16) _Float16 xtb[16][XSTRIDE];  // LN'd xt, f16
    __shared__ __align__(16) float2 stats[16][8];        // [row][wave] (sum, sumsq)
    __shared__ __align__(16) float res_lds[16][RSTRIDE]; // f32 residual

    const int tid  = threadIdx.x;
    const int w    = tid >> 6;
    const int lane = tid & 63;
    const int l15  = lane & 15;
    const int quad = lane >> 4;
    const int s0   = blockIdx.x * 2;
    const float k0 = (float)s0;

    // ---- stage x into xsb (f16) and res_lds (f32), one coalesced float4 pass
    {
        const float4* seq4 = (const float4*)seq;
        #pragma unroll
        for (int u = 0; u < 2; ++u) {
            int v  = tid + 512 * u;          // float4 index 0..1023
            int sl = v >> 9;
            int rm = v & 511;
            int b  = rm >> 6, j4 = rm & 63;
            float4 x = seq4[((size_t)b * SS + s0 + sl) * 64 + j4];
            int r = sl * 8 + b;
            half2t* dst = (half2t*)&xsb[r][4 * j4];
            dst[0] = pkrtz(x.x, x.y);
            dst[1] = pkrtz(x.z, x.w);
            *(float4*)&res_lds[r][4 * j4] = x;
        }
    }
    __syncthreads();

    #pragma unroll 1
    for (int layer = 0; layer < 2; ++layer) {
        const float* M  = layer ? M2  : M1;
        const float* P  = layer ? P2  : P1;
        const float* g  = layer ? g2  : g1;
        const float* be = layer ? be2 : be1;
        const char*  lbase = ws + (size_t)layer * LAYER_BYTES;
        const half8* Mtab = (const half8*)lbase;
        const half8* Ptab = (const half8*)(lbase + PTAB_OFF);

        // ======== phase A: xt = x @ M^T, distance-1 pipelined
        float4v acc1[2];
        acc1[0] = (float4v){0.f, 0.f, 0.f, 0.f};
        acc1[1] = (float4v){0.f, 0.f, 0.f, 0.f};

        half8 aN = *(const half8*)&xsb[l15][quad * 8];
        half8 b0N, b1N;
        if (TABS) {
            b0N = Mtab[(2 * w) * 64 + lane];
            b1N = Mtab[(2 * w + 1) * 64 + lane];
        }
        #pragma unroll 1
        for (int kt = 0; kt < 8; ++kt) {
            half8 aC = aN;
            half8 b0C, b1C;
            if (TABS) {
                b0C = b0N; b1C = b1N;
            } else {
                #pragma unroll
                for (int t = 0; t < 2; ++t) {
                    int n = 16 * (2 * w + t) + l15;
                    const float4* Mr = (const float4*)M + ((size_t)n * 64 + kt * 8 + quad * 2);
                    float4 m0 = Mr[0], m1 = Mr[1];
                    h8u bb2;
                    bb2.h2[0] = pkrtz(m0.x, m0.y);
                    bb2.h2[1] = pkrtz(m0.z, m0.w);
                    bb2.h2[2] = pkrtz(m1.x, m1.y);
                    bb2.h2[3] = pkrtz(m1.z, m1.w);
                    if (t == 0) b0C = bb2.h; else b1C = bb2.h;
                }
            }
            if (kt < 7) {
                aN = *(const half8*)&xsb[l15][(kt + 1) * 32 + quad * 8];
                if (TABS) {
                    b0N = Mtab[((kt + 1) * 16 + 2 * w) * 64 + lane];
                    b1N = Mtab[((kt + 1) * 16 + 2 * w + 1) * 64 + lane];
                }
            }
            acc1[0] = __builtin_amdgcn_mfma_f32_16x16x32_f16(aC, b0C, acc1[0], 0, 0, 0);
            acc1[1] = __builtin_amdgcn_mfma_f32_16x16x32_f16(aC, b1C, acc1[1], 0, 0, 0);
        }

        // issue phase-B's first Ptab loads NOW: LayerNorm below covers their latency
        half8 p0N, p1N;
        if (TABS) {
            p0N = Ptab[(2 * w) * 64 + lane];
            p1N = Ptab[(2 * w + 1) * 64 + lane];
        }

        // ======== LayerNorm in C-register layout (row m = quad*4+reg)
        #pragma unroll
        for (int reg = 0; reg < 4; ++reg) {
            float v0 = acc1[0][reg], v1 = acc1[1][reg];
            float sm = v0 + v1;
            float sq = fmaf(v0, v0, v1 * v1);
            #pragma unroll
            for (int off = 1; off < 16; off <<= 1) {
                sm += __shfl_xor(sm, off, 64);
                sq += __shfl_xor(sq, off, 64);
            }
            if (l15 == 0) stats[quad * 4 + reg][w] = make_float2(sm, sq);
        }
        __syncthreads();
        {
            int c0i = 16 * (2 * w) + l15, c1i = 16 * (2 * w + 1) + l15;
            float gv0 = g[c0i], bv0 = be[c0i];
            float gv1 = g[c1i], bv1 = be[c1i];
            #pragma unroll
            for (int reg = 0; reg < 4; ++reg) {
                int m = quad * 4 + reg;
                const float4* s4 = (const float4*)&stats[m][0];
                float4 q0 = s4[0], q1 = s4[1], q2 = s4[2], q3 = s4[3];
                float sm = (q0.x + q0.z) + (q1.x + q1.z) + (q2.x + q2.z) + (q3.x + q3.z);
                float sq = (q0.y + q0.w) + (q1.y + q1.w) + (q2.y + q2.w) + (q3.y + q3.w);
                float mm = sm * (1.f / DD);
                float rs = rsqrtf(sq * (1.f / DD) - mm * mm + 1e-5f);
                xtb[m][c0i] = (_Float16)fmaf((acc1[0][reg] - mm) * rs, gv0, bv0);
                xtb[m][c1i] = (_Float16)fmaf((acc1[1][reg] - mm) * rs, gv1, bv1);
            }
        }
        __syncthreads();   // xtb ready for phase B

        // ======== phase B: Nk = xt @ W_s^T; W = P * cos, 1/p via v_rcp (shared k0/k1)
        float4v accS[2][2];   // [s-half][t]
        #pragma unroll
        for (int k = 0; k < 2; ++k)
            #pragma unroll
            for (int t = 0; t < 2; ++t) accS[k][t] = (float4v){0.f, 0.f, 0.f, 0.f};

        // running period base (exact integer arithmetic in f32: values < 2^17)
        float fb0 = (float)((16 * (2 * w) + l15) * DD + quad * 8 + 2);
        float fb1 = fb0 + 16.0f * DD;   // t=1 tile: n += 16
        half8 aBN = *(const half8*)&xtb[l15][quad * 8];

        #pragma unroll 1
        for (int kt = 0; kt < 8; ++kt) {
            half8 aC = aBN;
            h8u p0C, p1C;
            if (TABS) {
                p0C.h = p0N; p1C.h = p1N;
            } else {
                #pragma unroll
                for (int t = 0; t < 2; ++t) {
                    int n = 16 * (2 * w + t) + l15;
                    const float4* Pr = (const float4*)P + ((size_t)n * 64 + kt * 8 + quad * 2);
                    float4 p0 = Pr[0], p1 = Pr[1];
                    h8u pv;
                    pv.h2[0] = pkrtz(p0.x, p0.y);
                    pv.h2[1] = pkrtz(p0.z, p0.w);
                    pv.h2[2] = pkrtz(p1.x, p1.y);
                    pv.h2[3] = pkrtz(p1.z, p1.w);
                    if (t == 0) p0C = pv; else p1C = pv;
                }
            }
            if (kt < 7) {
                aBN = *(const half8*)&xtb[l15][(kt + 1) * 32 + quad * 8];
                if (TABS) {
                    p0N = Ptab[((kt + 1) * 16 + 2 * w) * 64 + lane];
                    p1N = Ptab[((kt + 1) * 16 + 2 * w + 1) * 64 + lane];
                }
            }
            // ---- t = 0: n = 32w + l15; p >= 1026 > k for w >= 1 -> skip fract
            if (w == 0) {
                h8u bA, bB;
                #pragma unroll
                for (int e = 0; e < 4; ++e) {
                    float ia = __builtin_amdgcn_rcpf(fb0 + (float)(2 * e));
                    float ib = __builtin_amdgcn_rcpf(fb0 + (float)(2 * e + 1));
                    float a0 = k0 * ia, b0f = k0 * ib;
                    float a1 = a0 + ia, b1f = b0f + ib;   // (k0+1)/p
                    half2t c0 = pkrtz(cosrev(a0), cosrev(b0f));
                    half2t c1 = pkrtz(cosrev(a1), cosrev(b1f));
                    bA.h2[e] = p0C.h2[e] * c0;   // v_pk_mul_f16
                    bB.h2[e] = p0C.h2[e] * c1;
                }
                accS[0][0] = __builtin_amdgcn_mfma_f32_16x16x32_f16(aC, bA.h, accS[0][0], 0, 0, 0);
                accS[1][0] = __builtin_amdgcn_mfma_f32_16x16x32_f16(aC, bB.h, accS[1][0], 0, 0, 0);
            } else {
                h8u bA, bB;
                #pragma unroll
                for (int e = 0; e < 4; ++e) {
                    float ia = __builtin_amdgcn_rcpf(fb0 + (float)(2 * e));
                    float ib = __builtin_amdgcn_rcpf(fb0 + (float)(2 * e + 1));
                    float a0 = k0 * ia, b0f = k0 * ib;
                    float a1 = a0 + ia, b1f = b0f + ib;
                    half2t c0 = pkrtz(cosq(a0), cosq(b0f));
                    half2t c1 = pkrtz(cosq(a1), cosq(b1f));
                    bA.h2[e] = p0C.h2[e] * c0;
                    bB.h2[e] = p0C.h2[e] * c1;
                }
                accS[0][0] = __builtin_amdgcn_mfma_f32_16x16x32_f16(aC, bA.h, accS[0][0], 0, 0, 0);
                accS[1][0] = __builtin_amdgcn_mfma_f32_16x16x32_f16(aC, bB.h, accS[1][0], 0, 0, 0);
            }
            fb0 += 32.0f;
            // ---- t = 1: n = 32w + 16 + l15 >= 16 -> p >= 4098 > k always -> no fract
            {
                h8u bA, bB;
                #pragma unroll
                for (int e = 0; e < 4; ++e) {
                    float ia = __builtin_amdgcn_rcpf(fb1 + (float)(2 * e));
                    float ib = __builtin_amdgcn_rcpf(fb1 + (float)(2 * e + 1));
                    float a0 = k0 * ia, b0f = k0 * ib;
                    float a1 = a0 + ia, b1f = b0f + ib;
                    half2t c0 = pkrtz(cosq(a0), cosq(b0f));
                    half2t c1 = pkrtz(cosq(a1), cosq(b1f));
                    bA.h2[e] = p1C.h2[e] * c0;
                    bB.h2[e] = p1C.h2[e] * c1;
                }
                accS[0][1] = __builtin_amdgcn_mfma_f32_16x16x32_f16(aC, bA.h, accS[0][1], 0, 0, 0);
                accS[1][1] = __builtin_amdgcn_mfma_f32_16x16x32_f16(aC, bB.h, accS[1][1], 0, 0, 0);
                fb1 += 32.0f;
            }
        }

        // ======== epilogue: rows 0-7 (quads 0-1) = s0, rows 8-15 (quads 2-3) = s1
        #pragma unroll
        for (int t = 0; t < 2; ++t) {
            int col = 16 * (2 * w + t) + l15;
            float4v av = (quad < 2) ? accS[0][t] : accS[1][t];
            int sl = quad >> 1;
            #pragma unroll
            for (int reg = 0; reg < 4; ++reg) {
                int m = quad * 4 + reg;
                int b = m & 7;
                float val = av[reg] + res_lds[m][col];
                if (layer == 0) {
                    res_lds[m][col] = val;         // next layer's residual
                    xsb[m][col] = (_Float16)val;   // next layer's A-matrix
                } else {
                    out[((size_t)b * SS + s0 + sl) * DD + col] = val;
                }
            }
        }
        if (layer == 0) __syncthreads();
    }
}

extern "C" void kernel_launch(void* const* d_in, const int* in_sizes, int n_in,
                              void* d_out, int out_size, void* d_ws, size_t ws_size,
                              hipStream_t stream)
{
    const float* seq = (const float*)d_in[0];
    const float* M1  = (const float*)d_in[1];
    const float* P1  = (const float*)d_in[2];
    const float* g1  = (const float*)d_in[3];
    const float* b1  = (const float*)d_in[4];
    const float* M2  = (const float*)d_in[5];
    const float* P2  = (const float*)d_in[6];
    const float* g2  = (const float*)d_in[7];
    const float* b2  = (const float*)d_in[8];
    float* out = (float*)d_out;

    if (ws_size >= WS_NEEDED) {
        build_tabs<<<64, 256, 0, stream>>>(M1, P1, M2, P2, (char*)d_ws);
        fused_hierddpm<true><<<SS / 2, 512, 0, stream>>>(
            seq, M1, P1, g1, b1, M2, P2, g2, b2, (const char*)d_ws, out);
    } else {
        fused_hierddpm<false><<<SS / 2, 512, 0, stream>>>(
            seq, M1, P1, g1, b1, M2, P2, g2, b2, nullptr, out);
    }
}